// Round 3
// baseline (2605.215 us; speedup 1.0000x reference)
//
#include <hip/hip_runtime.h>
#include <hip/hip_bf16.h>

#define DEVFN __device__ __forceinline__

// Monotonic float -> uint key for atomicMax on floats.
DEVFN unsigned f2key(float f) {
  unsigned u = __float_as_uint(f);
  return (u & 0x80000000u) ? ~u : (u | 0x80000000u);
}
DEVFN float key2f(unsigned k) {
  unsigned u = (k & 0x80000000u) ? (k & 0x7FFFFFFFu) : ~k;
  return __uint_as_float(u);
}

// ---------------------------------------------------------------------------
// GEMM h = X @ W  (+ fused attention-score reduction e_src, e_dst per row)
// One block per node row; blockDim.x == C (64 or 128). All fp32.
// ---------------------------------------------------------------------------
__global__ void gemm_escore(const float* __restrict__ X,
                            const float* __restrict__ W,
                            const float* __restrict__ a_src,
                            const float* __restrict__ a_dst,
                            float* __restrict__ H,
                            float* __restrict__ es, float* __restrict__ ed,
                            int K, int C) {
  const int n = blockIdx.x;
  const int c = threadIdx.x;

  float acc = 0.f;
#pragma unroll 4
  for (int k = 0; k < K; ++k) {
    acc += X[(size_t)n * K + k] * W[(size_t)k * C + c];
  }
  H[(size_t)n * C + c] = acc;

  __shared__ float2 red[128];
  red[c] = make_float2(acc * a_src[c], acc * a_dst[c]);
  __syncthreads();
  for (int s = blockDim.x >> 1; s > 0; s >>= 1) {
    if (c < s) {
      red[c].x += red[c + s].x;
      red[c].y += red[c + s].y;
    }
    __syncthreads();
  }
  if (c == 0) {
    es[n] = red[0].x;
    ed[n] = red[0].y;
  }
}

// ---------------------------------------------------------------------------
// Edge pass 1: logit = leaky_relu(es[src] + ed[dst]); segment max via atomicMax
// Edges e in [0, E) from edge_index; e in [E, E+N) are self-loops.
// ---------------------------------------------------------------------------
__global__ void edge_logit_max(const int* __restrict__ src, const int* __restrict__ dst,
                               const float* __restrict__ es, const float* __restrict__ ed,
                               float* __restrict__ logit, unsigned* __restrict__ mkey,
                               int E, int N) {
  int e = blockIdx.x * blockDim.x + threadIdx.x;
  int ET = E + N;
  if (e >= ET) return;
  int s, d;
  if (e < E) { s = src[e]; d = dst[e]; } else { s = e - E; d = s; }
  float l = es[s] + ed[d];
  l = (l >= 0.f) ? l : 0.2f * l;
  logit[e] = l;
  atomicMax(mkey + d, f2key(l));
}

// ---------------------------------------------------------------------------
// Edge pass 2: den[dst] += exp(logit - m[dst])
// ---------------------------------------------------------------------------
__global__ void edge_exp_denom(const int* __restrict__ dst,
                               const float* __restrict__ logit,
                               const unsigned* __restrict__ mkey,
                               float* __restrict__ den,
                               int E, int N) {
  int e = blockIdx.x * blockDim.x + threadIdx.x;
  int ET = E + N;
  if (e >= ET) return;
  int d = (e < E) ? dst[e] : (e - E);
  float m = key2f(mkey[d]);
  float p = expf(logit[e] - m);
  atomicAdd(den + d, p);
}

// ---------------------------------------------------------------------------
// Edge pass 3: agg[dst] += (exp(logit-m[dst])/den[dst]) * H[src], 32 lanes/edge
// ---------------------------------------------------------------------------
__global__ void edge_aggregate(const int* __restrict__ src, const int* __restrict__ dst,
                               const float* __restrict__ H,
                               const float* __restrict__ logit,
                               const unsigned* __restrict__ mkey,
                               const float* __restrict__ den,
                               float* __restrict__ agg,
                               int E, int N, int C) {
  const int gper = blockDim.x >> 5;
  int g = blockIdx.x * gper + (threadIdx.x >> 5);
  int lane = threadIdx.x & 31;
  int ET = E + N;
  if (g >= ET) return;
  int s, d;
  if (g < E) { s = src[g]; d = dst[g]; } else { s = g - E; d = s; }
  float p = expf(logit[g] - key2f(mkey[d]));
  float alpha = p / den[d];
  const float* hs = H + (size_t)s * C;
  float* od = agg + (size_t)d * C;
  for (int c = lane; c < C; c += 32) {
    atomicAdd(od + c, alpha * hs[c]);
  }
}

// ---------------------------------------------------------------------------
// Epilogues: bias + ReLU in place (f32), or bias -> fp32 output.
// ---------------------------------------------------------------------------
__global__ void bias_relu_f32(float* __restrict__ X, const float* __restrict__ b, int C) {
  int n = blockIdx.x;
  int c = threadIdx.x;
  size_t i = (size_t)n * C + c;
  float v = X[i] + b[c];
  X[i] = (v > 0.f) ? v : 0.f;
}

__global__ void bias_out_f32(const float* __restrict__ X, const float* __restrict__ b,
                             float* __restrict__ out, int C) {
  int n = blockIdx.x;
  int c = threadIdx.x;
  size_t i = (size_t)n * C + c;
  out[i] = X[i] + b[c];
}

// ---------------------------------------------------------------------------

extern "C" void kernel_launch(void* const* d_in, const int* in_sizes, int n_in,
                              void* d_out, int out_size, void* d_ws, size_t ws_size,
                              hipStream_t stream) {
  const int C_HID = in_sizes[3];            // as0: [C_HID]
  const int C_FIN = in_sizes[11];           // as2: [C_OUT]
  const int C_IN  = in_sizes[2] / C_HID;    // W0: [C_IN, C_HID]
  const int N     = in_sizes[0] / C_IN;     // x: [N, C_IN]
  const int E     = in_sizes[1] / 2;        // edge_index: [2, E]
  const int ET    = E + N;

  const float* x = (const float*)d_in[0];
  const int* ei  = (const int*)d_in[1];
  const int* src = ei;
  const int* dst = ei + E;

  const float* W0  = (const float*)d_in[2];
  const float* as0 = (const float*)d_in[3];
  const float* ad0 = (const float*)d_in[4];
  const float* b0  = (const float*)d_in[5];
  const float* W1  = (const float*)d_in[6];
  const float* as1 = (const float*)d_in[7];
  const float* ad1 = (const float*)d_in[8];
  const float* b1  = (const float*)d_in[9];
  const float* W2  = (const float*)d_in[10];
  const float* as2 = (const float*)d_in[11];
  const float* ad2 = (const float*)d_in[12];
  const float* b2  = (const float*)d_in[13];

  // Workspace layout (256B aligned)
  char* base = (char*)d_ws;
  size_t off = 0;
  auto alloc = [&](size_t bytes) -> char* {
    char* p = base + off;
    off = (off + bytes + 255) & ~((size_t)255);
    return p;
  };
  float*    H   = (float*)alloc((size_t)N * C_HID * sizeof(float));
  float*    AGG = (float*)alloc((size_t)N * C_HID * sizeof(float));
  float*    ES  = (float*)alloc((size_t)N * sizeof(float));
  float*    ED  = (float*)alloc((size_t)N * sizeof(float));
  unsigned* MK  = (unsigned*)alloc((size_t)N * sizeof(unsigned));
  float*    DEN = (float*)alloc((size_t)N * sizeof(float));
  float*    LOG = (float*)alloc((size_t)ET * sizeof(float));
  (void)ws_size;

  const int ETHREADS = 256;
  const int egrid = (ET + ETHREADS - 1) / ETHREADS;
  const int agrid = (ET + (ETHREADS / 32) - 1) / (ETHREADS / 32);

  auto run_layer = [&](const float* X, int K, int C,
                       const float* W, const float* as_, const float* ad_,
                       const float* b_, float* final_out) {
    gemm_escore<<<N, C, 0, stream>>>(X, W, as_, ad_, H, ES, ED, K, C);

    hipMemsetAsync(MK, 0, (size_t)N * sizeof(unsigned), stream);
    hipMemsetAsync(DEN, 0, (size_t)N * sizeof(float), stream);
    hipMemsetAsync(AGG, 0, (size_t)N * C * sizeof(float), stream);

    edge_logit_max<<<egrid, ETHREADS, 0, stream>>>(src, dst, ES, ED, LOG, MK, E, N);
    edge_exp_denom<<<egrid, ETHREADS, 0, stream>>>(dst, LOG, MK, DEN, E, N);
    edge_aggregate<<<agrid, ETHREADS, 0, stream>>>(src, dst, H, LOG, MK, DEN, AGG, E, N, C);

    if (final_out)
      bias_out_f32<<<N, C, 0, stream>>>(AGG, b_, final_out, C);
    else
      bias_relu_f32<<<N, C, 0, stream>>>(AGG, b_, C);  // in place; AGG is next X
  };

  // Layer 0: x -> AGG (f32, relu'd)
  run_layer(x, C_IN, C_HID, W0, as0, ad0, b0, nullptr);
  // Layer 1: AGG -> AGG
  run_layer(AGG, C_HID, C_HID, W1, as1, ad1, b1, nullptr);
  // Layer 2: AGG -> d_out (f32)
  run_layer(AGG, C_HID, C_FIN, W2, as2, ad2, b2, (float*)d_out);
  (void)out_size; (void)n_in;
}

// Round 4
// 1273.448 us; speedup vs baseline: 2.0458x; 2.0458x over previous
//
#include <hip/hip_runtime.h>
#include <hip/hip_bf16.h>

#define DEVFN __device__ __forceinline__

DEVFN float lrelu(float v) { return (v >= 0.f) ? v : 0.2f * v; }

// ---------------------------------------------------------------------------
// GEMM h = X @ W  (+ fused attention-score reduction e_src, e_dst per row)
// One block per node row; blockDim.x == C (64 or 128). All fp32.
// ---------------------------------------------------------------------------
__global__ void gemm_escore(const float* __restrict__ X,
                            const float* __restrict__ W,
                            const float* __restrict__ a_src,
                            const float* __restrict__ a_dst,
                            float* __restrict__ H,
                            float* __restrict__ es, float* __restrict__ ed,
                            int K, int C) {
  const int n = blockIdx.x;
  const int c = threadIdx.x;

  float acc = 0.f;
#pragma unroll 4
  for (int k = 0; k < K; ++k) {
    acc += X[(size_t)n * K + k] * W[(size_t)k * C + c];
  }
  H[(size_t)n * C + c] = acc;

  __shared__ float2 red[128];
  red[c] = make_float2(acc * a_src[c], acc * a_dst[c]);
  __syncthreads();
  for (int s = blockDim.x >> 1; s > 0; s >>= 1) {
    if (c < s) {
      red[c].x += red[c + s].x;
      red[c].y += red[c + s].y;
    }
    __syncthreads();
  }
  if (c == 0) {
    es[n] = red[0].x;
    ed[n] = red[0].y;
  }
}

// ---------------------------------------------------------------------------
// CSR build: histogram -> single-block scan -> scatter. Rebuilt every launch
// (harness poisons d_ws), reused by all 3 layers.
// ---------------------------------------------------------------------------
__global__ void csr_count(const int* __restrict__ dst, int* __restrict__ deg, int E) {
  int e = blockIdx.x * blockDim.x + threadIdx.x;
  if (e < E) atomicAdd(deg + dst[e], 1);
}

__global__ void csr_scan(const int* __restrict__ deg, int* __restrict__ row_ptr,
                         int* __restrict__ wp, int N) {
  __shared__ int sh[256];
  __shared__ int carry;
  if (threadIdx.x == 0) carry = 0;
  __syncthreads();
  for (int base = 0; base < N; base += 256) {
    int i = base + threadIdx.x;
    int v = (i < N) ? deg[i] : 0;
    sh[threadIdx.x] = v;
    __syncthreads();
    for (int o = 1; o < 256; o <<= 1) {
      int t = (threadIdx.x >= o) ? sh[threadIdx.x - o] : 0;
      __syncthreads();
      sh[threadIdx.x] += t;
      __syncthreads();
    }
    int excl = sh[threadIdx.x] - v;
    if (i < N) {
      row_ptr[i] = carry + excl;
      wp[i] = carry + excl;
    }
    __syncthreads();
    if (threadIdx.x == 255) carry += sh[255];
    __syncthreads();
  }
  if (threadIdx.x == 0) row_ptr[N] = carry;
}

__global__ void csr_scatter(const int* __restrict__ src, const int* __restrict__ dst,
                            int* __restrict__ wp, int* __restrict__ col, int E) {
  int e = blockIdx.x * blockDim.x + threadIdx.x;
  if (e < E) {
    int p = atomicAdd(wp + dst[e], 1);
    col[p] = src[e];
  }
}

// ---------------------------------------------------------------------------
// Fused GAT aggregation: one wave (64 lanes) per dst node; CPL channels/lane.
// Online softmax over in-edges (self-loop first), then bias (+ReLU) and write.
// No atomics, coalesced output.
// ---------------------------------------------------------------------------
template<int CPL, bool RELU>
__global__ void gat_aggregate(const int* __restrict__ row_ptr,
                              const int* __restrict__ col,
                              const float* __restrict__ es,
                              const float* __restrict__ ed,
                              const float* __restrict__ H,
                              const float* __restrict__ bias,
                              float* __restrict__ outX, int N) {
  const int C = CPL * 64;
  const int wid = threadIdx.x >> 6;
  const int lane = threadIdx.x & 63;
  const int n = blockIdx.x * (blockDim.x >> 6) + wid;
  if (n >= N) return;

  const float edd = ed[n];
  // init with self-loop
  float m = lrelu(es[n] + edd);
  float denom = 1.f;
  float acc[CPL];
#pragma unroll
  for (int j = 0; j < CPL; ++j) acc[j] = H[(size_t)n * C + j * 64 + lane];

  const int k0 = row_ptr[n];
  const int k1 = row_ptr[n + 1];
  for (int k = k0; k < k1; ++k) {
    int s = col[k];
    float lg = lrelu(es[s] + edd);
    float mn = fmaxf(m, lg);
    float scale = __expf(m - mn);
    float p = __expf(lg - mn);
    denom = denom * scale + p;
    const float* hs = H + (size_t)s * C;
#pragma unroll
    for (int j = 0; j < CPL; ++j) acc[j] = acc[j] * scale + p * hs[j * 64 + lane];
    m = mn;
  }

  float inv = 1.f / denom;
  float* od = outX + (size_t)n * C;
#pragma unroll
  for (int j = 0; j < CPL; ++j) {
    float v = acc[j] * inv + bias[j * 64 + lane];
    if (RELU) v = (v > 0.f) ? v : 0.f;
    od[j * 64 + lane] = v;
  }
}

// ---------------------------------------------------------------------------

extern "C" void kernel_launch(void* const* d_in, const int* in_sizes, int n_in,
                              void* d_out, int out_size, void* d_ws, size_t ws_size,
                              hipStream_t stream) {
  const int C_HID = in_sizes[3];            // as0: [C_HID]
  const int C_FIN = in_sizes[11];           // as2: [C_OUT]
  const int C_IN  = in_sizes[2] / C_HID;    // W0: [C_IN, C_HID]
  const int N     = in_sizes[0] / C_IN;     // x: [N, C_IN]
  const int E     = in_sizes[1] / 2;        // edge_index: [2, E]

  const float* x = (const float*)d_in[0];
  const int* ei  = (const int*)d_in[1];
  const int* src = ei;
  const int* dst = ei + E;

  const float* W0  = (const float*)d_in[2];
  const float* as0 = (const float*)d_in[3];
  const float* ad0 = (const float*)d_in[4];
  const float* b0  = (const float*)d_in[5];
  const float* W1  = (const float*)d_in[6];
  const float* as1 = (const float*)d_in[7];
  const float* ad1 = (const float*)d_in[8];
  const float* b1  = (const float*)d_in[9];
  const float* W2  = (const float*)d_in[10];
  const float* as2 = (const float*)d_in[11];
  const float* ad2 = (const float*)d_in[12];
  const float* b2  = (const float*)d_in[13];

  // Workspace layout (256B aligned)
  char* base = (char*)d_ws;
  size_t off = 0;
  auto alloc = [&](size_t bytes) -> char* {
    char* p = base + off;
    off = (off + bytes + 255) & ~((size_t)255);
    return p;
  };
  float* H    = (float*)alloc((size_t)N * C_HID * sizeof(float));
  float* XB   = (float*)alloc((size_t)N * C_HID * sizeof(float));
  float* ES   = (float*)alloc((size_t)N * sizeof(float));
  float* ED   = (float*)alloc((size_t)N * sizeof(float));
  int*   RP   = (int*)alloc((size_t)(N + 1) * sizeof(int));
  int*   WP   = (int*)alloc((size_t)N * sizeof(int));
  int*   COL  = (int*)alloc((size_t)E * sizeof(int));
  int*   DEG  = (int*)alloc((size_t)N * sizeof(int));
  (void)ws_size;

  const int ET256 = (E + 255) / 256;

  // ---- CSR build (once; graph shared by all 3 layers) ----
  hipMemsetAsync(DEG, 0, (size_t)N * sizeof(int), stream);
  csr_count<<<ET256, 256, 0, stream>>>(dst, DEG, E);
  csr_scan<<<1, 256, 0, stream>>>(DEG, RP, WP, N);
  csr_scatter<<<ET256, 256, 0, stream>>>(src, dst, WP, COL, E);

  const int AGG_BLK = 256;                       // 4 waves / block
  const int agrid = (N + 3) / 4;

  // Layer 0: x -> H -> XB (relu)
  gemm_escore<<<N, C_HID, 0, stream>>>(x, W0, as0, ad0, H, ES, ED, C_IN, C_HID);
  gat_aggregate<2, true><<<agrid, AGG_BLK, 0, stream>>>(RP, COL, ES, ED, H, b0, XB, N);

  // Layer 1: XB -> H -> XB (relu)
  gemm_escore<<<N, C_HID, 0, stream>>>(XB, W1, as1, ad1, H, ES, ED, C_HID, C_HID);
  gat_aggregate<2, true><<<agrid, AGG_BLK, 0, stream>>>(RP, COL, ES, ED, H, b1, XB, N);

  // Layer 2: XB -> H -> d_out (no relu)
  gemm_escore<<<N, C_FIN, 0, stream>>>(XB, W2, as2, ad2, H, ES, ED, C_HID, C_FIN);
  gat_aggregate<1, false><<<agrid, AGG_BLK, 0, stream>>>(RP, COL, ES, ED, H, b2,
                                                         (float*)d_out, N);
  (void)out_size; (void)n_in;
}

// Round 5
// 1056.695 us; speedup vs baseline: 2.4654x; 1.2051x over previous
//
#include <hip/hip_runtime.h>
#include <hip/hip_bf16.h>

#define DEVFN __device__ __forceinline__

DEVFN float lrelu(float v) { return (v >= 0.f) ? v : 0.2f * v; }

// ---------------------------------------------------------------------------
// GEMM h = X @ W  (+ fused attention-score reduction e_src, e_dst per row)
// One block per node row; blockDim.x == C (64 or 128). All fp32.
// ---------------------------------------------------------------------------
__global__ void gemm_escore(const float* __restrict__ X,
                            const float* __restrict__ W,
                            const float* __restrict__ a_src,
                            const float* __restrict__ a_dst,
                            float* __restrict__ H,
                            float* __restrict__ es, float* __restrict__ ed,
                            int K, int C) {
  const int n = blockIdx.x;
  const int c = threadIdx.x;

  float acc = 0.f;
#pragma unroll 4
  for (int k = 0; k < K; ++k) {
    acc += X[(size_t)n * K + k] * W[(size_t)k * C + c];
  }
  H[(size_t)n * C + c] = acc;

  __shared__ float2 red[128];
  red[c] = make_float2(acc * a_src[c], acc * a_dst[c]);
  __syncthreads();
  for (int s = blockDim.x >> 1; s > 0; s >>= 1) {
    if (c < s) {
      red[c].x += red[c + s].x;
      red[c].y += red[c + s].y;
    }
    __syncthreads();
  }
  if (c == 0) {
    es[n] = red[0].x;
    ed[n] = red[0].y;
  }
}

// ---------------------------------------------------------------------------
// CSR build: histogram -> parallel 3-phase scan -> scatter.
// ---------------------------------------------------------------------------
__global__ void csr_count(const int* __restrict__ dst, int* __restrict__ deg, int E) {
  int e = blockIdx.x * blockDim.x + threadIdx.x;
  if (e < E) atomicAdd(deg + dst[e], 1);
}

// Phase 1: per-chunk (256 elems) sum.
__global__ void scan_partial(const int* __restrict__ deg, int* __restrict__ csum, int N) {
  __shared__ int sh[256];
  int i = blockIdx.x * 256 + threadIdx.x;
  sh[threadIdx.x] = (i < N) ? deg[i] : 0;
  __syncthreads();
  for (int o = 128; o > 0; o >>= 1) {
    if (threadIdx.x < o) sh[threadIdx.x] += sh[threadIdx.x + o];
    __syncthreads();
  }
  if (threadIdx.x == 0) csum[blockIdx.x] = sh[0];
}

// Phase 2: one block exclusive-scans the chunk sums (nch <= 256 handled in one
// tile; loop with carry for generality).
__global__ void scan_chunks(int* __restrict__ csum, int nch) {
  __shared__ int sh[256];
  __shared__ int carry;
  if (threadIdx.x == 0) carry = 0;
  __syncthreads();
  for (int base = 0; base < nch; base += 256) {
    int i = base + threadIdx.x;
    int v = (i < nch) ? csum[i] : 0;
    sh[threadIdx.x] = v;
    __syncthreads();
    for (int o = 1; o < 256; o <<= 1) {
      int t = (threadIdx.x >= o) ? sh[threadIdx.x - o] : 0;
      __syncthreads();
      sh[threadIdx.x] += t;
      __syncthreads();
    }
    if (i < nch) csum[i] = carry + sh[threadIdx.x] - v;
    __syncthreads();
    if (threadIdx.x == 255) carry += sh[255];
    __syncthreads();
  }
}

// Phase 3: local exclusive scan per chunk + chunk offset -> row_ptr & wp.
__global__ void scan_final(const int* __restrict__ deg, const int* __restrict__ csum,
                           int* __restrict__ rp, int* __restrict__ wp, int N, int E) {
  __shared__ int sh[256];
  int i = blockIdx.x * 256 + threadIdx.x;
  int v = (i < N) ? deg[i] : 0;
  sh[threadIdx.x] = v;
  __syncthreads();
  for (int o = 1; o < 256; o <<= 1) {
    int t = (threadIdx.x >= o) ? sh[threadIdx.x - o] : 0;
    __syncthreads();
    sh[threadIdx.x] += t;
    __syncthreads();
  }
  if (i < N) {
    int r = csum[blockIdx.x] + sh[threadIdx.x] - v;
    rp[i] = r;
    wp[i] = r;
  }
  if (blockIdx.x == 0 && threadIdx.x == 0) rp[N] = E;
}

__global__ void csr_scatter(const int* __restrict__ src, const int* __restrict__ dst,
                            int* __restrict__ wp, int* __restrict__ col, int E) {
  int e = blockIdx.x * blockDim.x + threadIdx.x;
  if (e < E) {
    int p = atomicAdd(wp + dst[e], 1);
    col[p] = src[e];
  }
}

// ---------------------------------------------------------------------------
// Fused GAT aggregation: one wave (64 lanes) per dst node; CPL channels/lane.
// Online softmax over in-edges (self-loop first), then bias (+ReLU) and write.
// No atomics, coalesced output.
// ---------------------------------------------------------------------------
template<int CPL, bool RELU>
__global__ void gat_aggregate(const int* __restrict__ row_ptr,
                              const int* __restrict__ col,
                              const float* __restrict__ es,
                              const float* __restrict__ ed,
                              const float* __restrict__ H,
                              const float* __restrict__ bias,
                              float* __restrict__ outX, int N) {
  const int C = CPL * 64;
  const int wid = threadIdx.x >> 6;
  const int lane = threadIdx.x & 63;
  const int n = blockIdx.x * (blockDim.x >> 6) + wid;
  if (n >= N) return;

  const float edd = ed[n];
  // init with self-loop
  float m = lrelu(es[n] + edd);
  float denom = 1.f;
  float acc[CPL];
#pragma unroll
  for (int j = 0; j < CPL; ++j) acc[j] = H[(size_t)n * C + j * 64 + lane];

  const int k0 = row_ptr[n];
  const int k1 = row_ptr[n + 1];
  for (int k = k0; k < k1; ++k) {
    int s = col[k];
    float lg = lrelu(es[s] + edd);
    float mn = fmaxf(m, lg);
    float scale = __expf(m - mn);
    float p = __expf(lg - mn);
    denom = denom * scale + p;
    const float* hs = H + (size_t)s * C;
#pragma unroll
    for (int j = 0; j < CPL; ++j) acc[j] = acc[j] * scale + p * hs[j * 64 + lane];
    m = mn;
  }

  float inv = 1.f / denom;
  float* od = outX + (size_t)n * C;
#pragma unroll
  for (int j = 0; j < CPL; ++j) {
    float v = acc[j] * inv + bias[j * 64 + lane];
    if (RELU) v = (v > 0.f) ? v : 0.f;
    od[j * 64 + lane] = v;
  }
}

// ---------------------------------------------------------------------------

extern "C" void kernel_launch(void* const* d_in, const int* in_sizes, int n_in,
                              void* d_out, int out_size, void* d_ws, size_t ws_size,
                              hipStream_t stream) {
  const int C_HID = in_sizes[3];            // as0: [C_HID]
  const int C_FIN = in_sizes[11];           // as2: [C_OUT]
  const int C_IN  = in_sizes[2] / C_HID;    // W0: [C_IN, C_HID]
  const int N     = in_sizes[0] / C_IN;     // x: [N, C_IN]
  const int E     = in_sizes[1] / 2;        // edge_index: [2, E]

  const float* x = (const float*)d_in[0];
  const int* ei  = (const int*)d_in[1];
  const int* src = ei;
  const int* dst = ei + E;

  const float* W0  = (const float*)d_in[2];
  const float* as0 = (const float*)d_in[3];
  const float* ad0 = (const float*)d_in[4];
  const float* b0  = (const float*)d_in[5];
  const float* W1  = (const float*)d_in[6];
  const float* as1 = (const float*)d_in[7];
  const float* ad1 = (const float*)d_in[8];
  const float* b1  = (const float*)d_in[9];
  const float* W2  = (const float*)d_in[10];
  const float* as2 = (const float*)d_in[11];
  const float* ad2 = (const float*)d_in[12];
  const float* b2  = (const float*)d_in[13];

  // Workspace layout (256B aligned)
  char* base = (char*)d_ws;
  size_t off = 0;
  auto alloc = [&](size_t bytes) -> char* {
    char* p = base + off;
    off = (off + bytes + 255) & ~((size_t)255);
    return p;
  };
  const int NCH = (N + 255) / 256;
  float* H    = (float*)alloc((size_t)N * C_HID * sizeof(float));
  float* XB   = (float*)alloc((size_t)N * C_HID * sizeof(float));
  float* ES   = (float*)alloc((size_t)N * sizeof(float));
  float* ED   = (float*)alloc((size_t)N * sizeof(float));
  int*   RP   = (int*)alloc((size_t)(N + 1) * sizeof(int));
  int*   WP   = (int*)alloc((size_t)N * sizeof(int));
  int*   COL  = (int*)alloc((size_t)E * sizeof(int));
  int*   DEG  = (int*)alloc((size_t)N * sizeof(int));
  int*   CSUM = (int*)alloc((size_t)NCH * sizeof(int));
  (void)ws_size;

  const int ET256 = (E + 255) / 256;

  // ---- CSR build (once; graph shared by all 3 layers) ----
  hipMemsetAsync(DEG, 0, (size_t)N * sizeof(int), stream);
  csr_count<<<ET256, 256, 0, stream>>>(dst, DEG, E);
  scan_partial<<<NCH, 256, 0, stream>>>(DEG, CSUM, N);
  scan_chunks<<<1, 256, 0, stream>>>(CSUM, NCH);
  scan_final<<<NCH, 256, 0, stream>>>(DEG, CSUM, RP, WP, N, E);
  csr_scatter<<<ET256, 256, 0, stream>>>(src, dst, WP, COL, E);

  const int AGG_BLK = 256;                       // 4 waves / block
  const int agrid = (N + 3) / 4;

  // Layer 0: x -> H -> XB (relu)
  gemm_escore<<<N, C_HID, 0, stream>>>(x, W0, as0, ad0, H, ES, ED, C_IN, C_HID);
  gat_aggregate<2, true><<<agrid, AGG_BLK, 0, stream>>>(RP, COL, ES, ED, H, b0, XB, N);

  // Layer 1: XB -> H -> XB (relu)
  gemm_escore<<<N, C_HID, 0, stream>>>(XB, W1, as1, ad1, H, ES, ED, C_HID, C_HID);
  gat_aggregate<2, true><<<agrid, AGG_BLK, 0, stream>>>(RP, COL, ES, ED, H, b1, XB, N);

  // Layer 2: XB -> H -> d_out (no relu)
  gemm_escore<<<N, C_FIN, 0, stream>>>(XB, W2, as2, ad2, H, ES, ED, C_HID, C_FIN);
  gat_aggregate<1, false><<<agrid, AGG_BLK, 0, stream>>>(RP, COL, ES, ED, H, b2,
                                                         (float*)d_out, N);
  (void)out_size; (void)n_in;
}

// Round 6
// 834.658 us; speedup vs baseline: 3.1213x; 1.2660x over previous
//
#include <hip/hip_runtime.h>
#include <hip/hip_bf16.h>

#define DEVFN __device__ __forceinline__

DEVFN float lrelu(float v) { return (v >= 0.f) ? v : 0.2f * v; }

DEVFN float wave_sum(float v) {
#pragma unroll
  for (int o = 1; o < 64; o <<= 1) v += __shfl_xor(v, o, 64);
  return v;
}
DEVFN float wave_max(float v) {
#pragma unroll
  for (int o = 1; o < 64; o <<= 1) v = fmaxf(v, __shfl_xor(v, o, 64));
  return v;
}

// ---------------------------------------------------------------------------
// Tiled GEMM H = X @ W.  K=128 fixed; C in {64,128}. ROWS=16 rows per block,
// 256 threads. W fully staged in LDS (K*C floats), X tile staged too.
// ---------------------------------------------------------------------------
template<int K, int C>
__global__ __launch_bounds__(256) void gemm_tiled(const float* __restrict__ X,
                                                  const float* __restrict__ W,
                                                  float* __restrict__ H, int N) {
  constexpr int ROWS = 16;
  constexpr int TM = ROWS / (256 / C);   // 8 for C=128, 4 for C=64
  __shared__ float Ws[K * C];
  __shared__ float Xs[ROWS * K];

  const int t = threadIdx.x;
  const int row0 = blockIdx.x * ROWS;
  const int nrow = min(ROWS, N - row0);

  // stage W (once per block)
  const float4* Wv = (const float4*)W;
#pragma unroll 4
  for (int i = t; i < K * C / 4; i += 256) ((float4*)Ws)[i] = Wv[i];
  // stage X tile
  const float4* Xv = (const float4*)(X + (size_t)row0 * K);
  const int xcnt = nrow * K / 4;
  for (int i = t; i < xcnt; i += 256) ((float4*)Xs)[i] = Xv[i];
  __syncthreads();

  const int c = t % C;
  const int g = t / C;
  float acc[TM];
#pragma unroll
  for (int r = 0; r < TM; ++r) acc[r] = 0.f;

#pragma unroll 2
  for (int k = 0; k < K; k += 4) {
    float w0 = Ws[(k + 0) * C + c];
    float w1 = Ws[(k + 1) * C + c];
    float w2 = Ws[(k + 2) * C + c];
    float w3 = Ws[(k + 3) * C + c];
#pragma unroll
    for (int r = 0; r < TM; ++r) {
      float4 xv = *(const float4*)&Xs[(g * TM + r) * K + k];
      acc[r] += xv.x * w0 + xv.y * w1 + xv.z * w2 + xv.w * w3;
    }
  }
#pragma unroll
  for (int r = 0; r < TM; ++r) {
    int row = g * TM + r;
    if (row < nrow) H[(size_t)(row0 + row) * C + c] = acc[r];
  }
}

// ---------------------------------------------------------------------------
// Attention scores per node: es = h . a_src, ed = h . a_dst. One wave/node.
// ---------------------------------------------------------------------------
template<int C>
__global__ void escore(const float* __restrict__ H,
                       const float* __restrict__ a_src,
                       const float* __restrict__ a_dst,
                       float* __restrict__ es, float* __restrict__ ed, int N) {
  const int lane = threadIdx.x & 63;
  const int n = blockIdx.x * (blockDim.x >> 6) + (threadIdx.x >> 6);
  if (n >= N) return;
  float ps, pd;
  if (C == 128) {
    float2 h = ((const float2*)H)[(size_t)n * 64 + lane];
    float2 as_ = ((const float2*)a_src)[lane];
    float2 ad_ = ((const float2*)a_dst)[lane];
    ps = h.x * as_.x + h.y * as_.y;
    pd = h.x * ad_.x + h.y * ad_.y;
  } else {
    float h = H[(size_t)n * C + lane];
    ps = h * a_src[lane];
    pd = h * a_dst[lane];
  }
  ps = wave_sum(ps);
  pd = wave_sum(pd);
  if (lane == 0) { es[n] = ps; ed[n] = pd; }
}

// ---------------------------------------------------------------------------
// CSR build: histogram -> parallel 3-phase scan -> scatter.
// ---------------------------------------------------------------------------
__global__ void csr_count(const int* __restrict__ dst, int* __restrict__ deg, int E) {
  int e = blockIdx.x * blockDim.x + threadIdx.x;
  if (e < E) atomicAdd(deg + dst[e], 1);
}

__global__ void scan_partial(const int* __restrict__ deg, int* __restrict__ csum, int N) {
  __shared__ int sh[256];
  int i = blockIdx.x * 256 + threadIdx.x;
  sh[threadIdx.x] = (i < N) ? deg[i] : 0;
  __syncthreads();
  for (int o = 128; o > 0; o >>= 1) {
    if (threadIdx.x < o) sh[threadIdx.x] += sh[threadIdx.x + o];
    __syncthreads();
  }
  if (threadIdx.x == 0) csum[blockIdx.x] = sh[0];
}

__global__ void scan_chunks(int* __restrict__ csum, int nch) {
  __shared__ int sh[256];
  __shared__ int carry;
  if (threadIdx.x == 0) carry = 0;
  __syncthreads();
  for (int base = 0; base < nch; base += 256) {
    int i = base + threadIdx.x;
    int v = (i < nch) ? csum[i] : 0;
    sh[threadIdx.x] = v;
    __syncthreads();
    for (int o = 1; o < 256; o <<= 1) {
      int t = (threadIdx.x >= o) ? sh[threadIdx.x - o] : 0;
      __syncthreads();
      sh[threadIdx.x] += t;
      __syncthreads();
    }
    if (i < nch) csum[i] = carry + sh[threadIdx.x] - v;
    __syncthreads();
    if (threadIdx.x == 255) carry += sh[255];
    __syncthreads();
  }
}

__global__ void scan_final(const int* __restrict__ deg, const int* __restrict__ csum,
                           int* __restrict__ rp, int* __restrict__ wp, int N, int E) {
  __shared__ int sh[256];
  int i = blockIdx.x * 256 + threadIdx.x;
  int v = (i < N) ? deg[i] : 0;
  sh[threadIdx.x] = v;
  __syncthreads();
  for (int o = 1; o < 256; o <<= 1) {
    int t = (threadIdx.x >= o) ? sh[threadIdx.x - o] : 0;
    __syncthreads();
    sh[threadIdx.x] += t;
    __syncthreads();
  }
  if (i < N) {
    int r = csum[blockIdx.x] + sh[threadIdx.x] - v;
    rp[i] = r;
    wp[i] = r;
  }
  if (blockIdx.x == 0 && threadIdx.x == 0) rp[N] = E;
}

__global__ void csr_scatter(const int* __restrict__ src, const int* __restrict__ dst,
                            int* __restrict__ wp, int* __restrict__ col, int E) {
  int e = blockIdx.x * blockDim.x + threadIdx.x;
  if (e < E) {
    int p = atomicAdd(wp + dst[e], 1);
    col[p] = src[e];
  }
}

// ---------------------------------------------------------------------------
// Edge softmax per dst node: one wave/node, lanes parallel over in-edges.
// Writes unnormalized p per edge (ALPHA), plus DEN and SELFP per node.
// ---------------------------------------------------------------------------
__global__ void attn_softmax(const int* __restrict__ row_ptr,
                             const int* __restrict__ col,
                             const float* __restrict__ es,
                             const float* __restrict__ ed,
                             float* __restrict__ alpha,
                             float* __restrict__ den_out,
                             float* __restrict__ selfp_out, int N) {
  const int lane = threadIdx.x & 63;
  const int n = blockIdx.x * (blockDim.x >> 6) + (threadIdx.x >> 6);
  if (n >= N) return;

  const int k0 = row_ptr[n];
  const int k1 = row_ptr[n + 1];
  const int deg = k1 - k0;
  const float edd = ed[n];
  const float self_lg = lrelu(es[n] + edd);

  if (deg <= 64) {
    // fast path: whole row in registers
    int k = k0 + lane;
    bool act = (k < k1);
    float lg = act ? lrelu(es[col[k]] + edd) : -3.0e38f;
    float m = fmaxf(wave_max(lg), self_lg);
    float p = act ? __expf(lg - m) : 0.f;
    float den = wave_sum(p);
    float sp = __expf(self_lg - m);
    den += sp;
    if (act) alpha[k] = p;
    if (lane == 0) { den_out[n] = den; selfp_out[n] = sp; }
  } else {
    // general path: spill lg through alpha[]
    float m = self_lg;
    for (int base = k0; base < k1; base += 64) {
      int k = base + lane;
      if (k < k1) {
        float lg = lrelu(es[col[k]] + edd);
        alpha[k] = lg;
        m = fmaxf(m, lg);
      }
    }
    m = wave_max(m);
    float den = 0.f;
    for (int base = k0; base < k1; base += 64) {
      int k = base + lane;
      if (k < k1) {
        float p = __expf(alpha[k] - m);
        alpha[k] = p;
        den += p;
      }
    }
    den = wave_sum(den);
    float sp = __expf(self_lg - m);
    den += sp;
    if (lane == 0) { den_out[n] = den; selfp_out[n] = sp; }
  }
}

// ---------------------------------------------------------------------------
// Lean aggregation: one wave/node; acc += p * H[src]; no exp, no rescale.
// C=128: float2 per lane. C=64: float per lane. Bias (+ReLU) fused.
// ---------------------------------------------------------------------------
template<bool RELU>
__global__ void gat_gather128(const int* __restrict__ row_ptr,
                              const int* __restrict__ col,
                              const float* __restrict__ H,
                              const float* __restrict__ alpha,
                              const float* __restrict__ den,
                              const float* __restrict__ selfp,
                              const float* __restrict__ bias,
                              float* __restrict__ outX, int N) {
  const int lane = threadIdx.x & 63;
  const int n = blockIdx.x * (blockDim.x >> 6) + (threadIdx.x >> 6);
  if (n >= N) return;

  const float2* Hp = (const float2*)H;
  float sp = selfp[n];
  float2 hv = Hp[(size_t)n * 64 + lane];
  float ax = sp * hv.x, ay = sp * hv.y;

  const int k0 = row_ptr[n];
  const int k1 = row_ptr[n + 1];
#pragma unroll 2
  for (int k = k0; k < k1; ++k) {
    int s = col[k];
    float p = alpha[k];
    float2 h = Hp[(size_t)s * 64 + lane];
    ax += p * h.x;
    ay += p * h.y;
  }
  float inv = 1.f / den[n];
  float2 bv = ((const float2*)bias)[lane];
  float vx = ax * inv + bv.x;
  float vy = ay * inv + bv.y;
  if (RELU) { vx = fmaxf(vx, 0.f); vy = fmaxf(vy, 0.f); }
  ((float2*)outX)[(size_t)n * 64 + lane] = make_float2(vx, vy);
}

template<bool RELU>
__global__ void gat_gather64(const int* __restrict__ row_ptr,
                             const int* __restrict__ col,
                             const float* __restrict__ H,
                             const float* __restrict__ alpha,
                             const float* __restrict__ den,
                             const float* __restrict__ selfp,
                             const float* __restrict__ bias,
                             float* __restrict__ outX, int N) {
  const int lane = threadIdx.x & 63;
  const int n = blockIdx.x * (blockDim.x >> 6) + (threadIdx.x >> 6);
  if (n >= N) return;

  float acc = selfp[n] * H[(size_t)n * 64 + lane];
  const int k0 = row_ptr[n];
  const int k1 = row_ptr[n + 1];
#pragma unroll 2
  for (int k = k0; k < k1; ++k) {
    int s = col[k];
    float p = alpha[k];
    acc += p * H[(size_t)s * 64 + lane];
  }
  float v = acc / den[n] + bias[lane];
  if (RELU) v = fmaxf(v, 0.f);
  outX[(size_t)n * 64 + lane] = v;
}

// ---------------------------------------------------------------------------

extern "C" void kernel_launch(void* const* d_in, const int* in_sizes, int n_in,
                              void* d_out, int out_size, void* d_ws, size_t ws_size,
                              hipStream_t stream) {
  const int C_HID = in_sizes[3];            // 128
  const int C_FIN = in_sizes[11];           // 64
  const int C_IN  = in_sizes[2] / C_HID;    // 128
  const int N     = in_sizes[0] / C_IN;     // 50000
  const int E     = in_sizes[1] / 2;        // 1.6M

  const float* x = (const float*)d_in[0];
  const int* ei  = (const int*)d_in[1];
  const int* src = ei;
  const int* dst = ei + E;

  const float* W0  = (const float*)d_in[2];
  const float* as0 = (const float*)d_in[3];
  const float* ad0 = (const float*)d_in[4];
  const float* b0  = (const float*)d_in[5];
  const float* W1  = (const float*)d_in[6];
  const float* as1 = (const float*)d_in[7];
  const float* ad1 = (const float*)d_in[8];
  const float* b1  = (const float*)d_in[9];
  const float* W2  = (const float*)d_in[10];
  const float* as2 = (const float*)d_in[11];
  const float* ad2 = (const float*)d_in[12];
  const float* b2  = (const float*)d_in[13];

  // Workspace layout (256B aligned)
  char* base = (char*)d_ws;
  size_t off = 0;
  auto alloc = [&](size_t bytes) -> char* {
    char* p = base + off;
    off = (off + bytes + 255) & ~((size_t)255);
    return p;
  };
  const int NCH = (N + 255) / 256;
  float* H     = (float*)alloc((size_t)N * C_HID * sizeof(float));
  float* XB    = (float*)alloc((size_t)N * C_HID * sizeof(float));
  float* ES    = (float*)alloc((size_t)N * sizeof(float));
  float* ED    = (float*)alloc((size_t)N * sizeof(float));
  float* DEN   = (float*)alloc((size_t)N * sizeof(float));
  float* SELFP = (float*)alloc((size_t)N * sizeof(float));
  float* ALPHA = (float*)alloc((size_t)E * sizeof(float));
  int*   RP    = (int*)alloc((size_t)(N + 1) * sizeof(int));
  int*   WP    = (int*)alloc((size_t)N * sizeof(int));
  int*   COL   = (int*)alloc((size_t)E * sizeof(int));
  int*   DEG   = (int*)alloc((size_t)N * sizeof(int));
  int*   CSUM  = (int*)alloc((size_t)NCH * sizeof(int));
  (void)ws_size;

  const int ET256 = (E + 255) / 256;
  const int wgrid = (N + 3) / 4;     // 4 waves (256 thr) per block kernels
  const int ggrid = (N + 15) / 16;   // gemm: 16 rows per block

  // ---- CSR build (once; graph shared by all 3 layers) ----
  hipMemsetAsync(DEG, 0, (size_t)N * sizeof(int), stream);
  csr_count<<<ET256, 256, 0, stream>>>(dst, DEG, E);
  scan_partial<<<NCH, 256, 0, stream>>>(DEG, CSUM, N);
  scan_chunks<<<1, 256, 0, stream>>>(CSUM, NCH);
  scan_final<<<NCH, 256, 0, stream>>>(DEG, CSUM, RP, WP, N, E);
  csr_scatter<<<ET256, 256, 0, stream>>>(src, dst, WP, COL, E);

  // ---- Layer 0: x -> H -> XB (relu) ----
  gemm_tiled<128, 128><<<ggrid, 256, 0, stream>>>(x, W0, H, N);
  escore<128><<<wgrid, 256, 0, stream>>>(H, as0, ad0, ES, ED, N);
  attn_softmax<<<wgrid, 256, 0, stream>>>(RP, COL, ES, ED, ALPHA, DEN, SELFP, N);
  gat_gather128<true><<<wgrid, 256, 0, stream>>>(RP, COL, H, ALPHA, DEN, SELFP, b0, XB, N);

  // ---- Layer 1: XB -> H -> XB (relu) ----
  gemm_tiled<128, 128><<<ggrid, 256, 0, stream>>>(XB, W1, H, N);
  escore<128><<<wgrid, 256, 0, stream>>>(H, as1, ad1, ES, ED, N);
  attn_softmax<<<wgrid, 256, 0, stream>>>(RP, COL, ES, ED, ALPHA, DEN, SELFP, N);
  gat_gather128<true><<<wgrid, 256, 0, stream>>>(RP, COL, H, ALPHA, DEN, SELFP, b1, XB, N);

  // ---- Layer 2: XB -> H -> d_out (no relu) ----
  gemm_tiled<128, 64><<<ggrid, 256, 0, stream>>>(XB, W2, H, N);
  escore<64><<<wgrid, 256, 0, stream>>>(H, as2, ad2, ES, ED, N);
  attn_softmax<<<wgrid, 256, 0, stream>>>(RP, COL, ES, ED, ALPHA, DEN, SELFP, N);
  gat_gather64<false><<<wgrid, 256, 0, stream>>>(RP, COL, H, ALPHA, DEN, SELFP, b2,
                                                 (float*)d_out, N);
  (void)out_size; (void)n_in;
}